// Round 8
// baseline (126.610 us; speedup 1.0000x reference)
//
#include <hip/hip_runtime.h>
#include <hip/hip_bf16.h>
#include <stdint.h>

#define HH 128
#define WW 128
#define HWPX 16384
#define BIGL 16384           // background sentinel
#define NT 1024
#define PPT 16               // contiguous pixels per thread (one 16-col row chunk)

// find with path-halving via atomicMin (monotone decrease -> always acyclic,
// safe under concurrent unions; R4-validated, fastest variant measured)
__device__ __forceinline__ int findRootH(int* L, int x) {
    int p = L[x];
    while (p != x) {
        int g = L[p];
        if (g != p) atomicMin(&L[x], g);   // halving: g is ancestor, g < p
        x = p; p = g;
    }
    return x;
}
// post-merge find with plain-store halving (no concurrent unions)
__device__ __forceinline__ int findRootF(int* L, int x) {
    int p = L[x];
    while (p != x) {
        int g = L[p];
        if (g != p) L[x] = g;
        x = p; p = g;
    }
    return p;
}
// lock-free union by min index
__device__ __forceinline__ void uni(int* L, int a, int b) {
    a = findRootH(L, a);
    b = findRootH(L, b);
    while (a != b) {
        if (a > b) { int t = a; a = b; b = t; }
        int old = atomicMin(&L[b], a);
        if (old == b) break;
        b = findRootH(L, old);
    }
}

__device__ __forceinline__ int wsumi(int v)    { for (int o = 32; o; o >>= 1) v += __shfl_xor(v, o, 64); return v; }
__device__ __forceinline__ float wsumf(float v){ for (int o = 32; o; o >>= 1) v += __shfl_xor(v, o, 64); return v; }
__device__ __forceinline__ int wmini(int v)    { for (int o = 32; o; o >>= 1) v = min(v, __shfl_xor(v, o, 64)); return v; }
__device__ __forceinline__ int wmaxi(int v)    { for (int o = 32; o; o >>= 1) v = max(v, __shfl_xor(v, o, 64)); return v; }

__global__ __launch_bounds__(NT)
void cc_kernel(const float* __restrict__ masks, float* __restrict__ losses) {
    __shared__ int L[HWPX];              // 64 KB: UF parent; roots get area<<16
    __shared__ unsigned rowbits[HH][4];  // 2 KB: fg bitmap
    __shared__ int s_bg;
    __shared__ int s_r0, s_r1, s_c0, s_c1;
    __shared__ unsigned s_k2;
    __shared__ unsigned s_wk[32];
    __shared__ float s_wsum[16];
    __shared__ float s_total;

    const int tid = threadIdx.x;
    const int lane = tid & 63;
    const int wid = tid >> 6;
    const float* msk = masks + (size_t)blockIdx.x * HWPX;
    const int base = tid * PPT;
    const int row  = base >> 7;
    const int col0 = base & 127;

    // ---- vectorized load, fg detect, total sum, run-head labels in regs ----
    float vals[PPT];
    const float4* m4 = (const float4*)(msk + base);
#pragma unroll
    for (int q = 0; q < 4; ++q) {
        float4 v = m4[q];
        vals[q * 4 + 0] = v.x; vals[q * 4 + 1] = v.y;
        vals[q * 4 + 2] = v.z; vals[q * 4 + 3] = v.w;
    }
    unsigned fgbits = 0;
    float tsum = 0.f;
    int lab[PPT];
    {
        int start = -1;
#pragma unroll
        for (int k = 0; k < PPT; ++k) {
            tsum += vals[k];
            if (vals[k] > 0.f) {
                fgbits |= 1u << k;
                if (start < 0) start = k;
                lab[k] = base + start;
            } else {
                start = -1;
                lab[k] = BIGL;
            }
        }
    }
    // vectorized label init: 4x ds_write_b128
    {
        int4* Lv = (int4*)(L + base);
#pragma unroll
        for (int q = 0; q < 4; ++q)
            Lv[q] = make_int4(lab[q * 4], lab[q * 4 + 1], lab[q * 4 + 2], lab[q * 4 + 3]);
    }
    unsigned lf = __shfl(fgbits, lane > 0 ? lane - 1 : lane, 64);
    unsigned rf = __shfl(fgbits, lane < 63 ? lane + 1 : lane, 64);
    const unsigned leftbit  = (col0 > 0)   ? ((lf >> 15) & 1u) : 0u;
    const unsigned rightbit = (col0 < 112) ? (rf & 1u)         : 0u;
    unsigned other = __shfl_xor(fgbits, 1, 64);
    if (!(tid & 1)) rowbits[row][(tid >> 1) & 3] = fgbits | (other << 16);

    tsum = wsumf(tsum);
    if (lane == 0) s_wsum[wid] = tsum;
    if (tid == 0) { s_bg = 0; s_r0 = HH; s_r1 = -1; s_c0 = WW; s_c1 = -1; }
    __syncthreads();

    // ---- wave0: total ----
    if (tid < 64) {
        float t = (tid < 16) ? s_wsum[tid] : 0.f;
        for (int o = 8; o; o >>= 1) t += __shfl_xor(t, o, 64);
        if (tid == 0) s_total = t;
    }

    // ---- merge: level-synchronized strip merging (contention-free) ----
    // Boundary with lower-row R is processed at level ctz(R); a barrier between
    // levels confines each level's unions to independent 2^(l+1)-row strips.
    unsigned ULv = 0, UPv = 0, URv = 0, lFv = 0, rFv = 0, evmask = 0;
    if (fgbits) {
        unsigned up = 0;
        if (row > 0) {
            const int wi  = col0 >> 5;
            const int off = col0 & 31;
            unsigned w0 = rowbits[row - 1][wi];
            unsigned w1 = (wi < 3) ? rowbits[row - 1][wi + 1] : 0u;
            unsigned long long uv = ((unsigned long long)w1 << 32) | w0;
            if (off == 16) {
                up = (unsigned)(uv >> 15) & 0x3FFFFu;
            } else {
                unsigned lw = (col0 > 0) ? rowbits[row - 1][wi - 1] : 0u;
                up = (unsigned)((uv << 1) | (lw >> 31)) & 0x3FFFFu;
            }
        }
        ULv = up & 0xFFFFu;
        UPv = (up >> 1) & 0xFFFFu;
        URv = (up >> 2) & 0xFFFFu;
        lFv = ((fgbits << 1) | leftbit) & 0xFFFFu;
        rFv = (fgbits >> 1) | (rightbit << 15);
        evmask = fgbits & ( (~lFv & (ULv | UPv | URv))
                          | (lFv & ((UPv & ~ULv) | (~rFv & URv & ~UPv))) );
        // horizontal chunk-boundary stitch (independent per row, low contention)
        if ((fgbits & 1u) && leftbit) uni(L, base, base - 1);
    }
    const int mylvl = (row > 0) ? __builtin_ctz(row) : 7;
#pragma unroll 1
    for (int l = 0; l < 7; ++l) {
        if (mylvl == l && evmask) {
            unsigned m = evmask;
            while (m) {
                int k = __ffs(m) - 1; m &= m - 1;
                int i = base + k;
                unsigned UL = (ULv >> k) & 1u;
                unsigned UP = (UPv >> k) & 1u;
                unsigned UR = (URv >> k) & 1u;
                unsigned lF = (lFv >> k) & 1u;
                unsigned rF = (rFv >> k) & 1u;
                if (!lF) {
                    if (UL)        uni(L, i, i - WW - 1);
                    if (UP && !UL) uni(L, i, i - WW);
                    if (UR && !UP) uni(L, i, i - WW + 1);
                } else {
                    if (UP && !UL)        uni(L, i, i - WW);
                    if (!rF && UR && !UP) uni(L, i, i - WW + 1);
                }
            }
        }
        __syncthreads();
    }

    // ---- flatten: one find per run; compress run heads; track first root ----
    int rr[PPT];
    int firstRoot = 0x7FFFFFFF;
    {
        int cur = -1;
#pragma unroll
        for (int k = 0; k < PPT; ++k) {
            rr[k] = -1;
            if (fgbits & (1u << k)) {
                if (k == 0 || !(fgbits & (1u << (k - 1)))) {
                    cur = findRootF(L, base + k);
                    L[base + k] = cur;
                }
                rr[k] = cur;
                if (firstRoot == 0x7FFFFFFF) firstRoot = cur;
            }
        }
    }
    __syncthreads();

    // ---- areas: wave-combined for dominant root, run-length for the rest ----
    {
        const int R0 = wmini(firstRoot);          // wave-uniform hot root
        int giant = 0, bgc = 0, prev = -1, cnt = 0;
#pragma unroll
        for (int k = 0; k < PPT; ++k) {
            if (!(fgbits & (1u << k))) { ++bgc; continue; }
            int r = rr[k];
            if (r == R0) { ++giant; }
            else if (r == prev) ++cnt;
            else {
                if (cnt) atomicAdd(&L[prev], cnt << 16);
                prev = r; cnt = 1;
            }
        }
        if (cnt) atomicAdd(&L[prev], cnt << 16);
        int g = wsumi(giant);
        if (lane == 0 && R0 != 0x7FFFFFFF && g) atomicAdd(&L[R0], g << 16);
        int b = wsumi(bgc);
        if (lane == 0 && b) atomicAdd(&s_bg, b);
    }
    __syncthreads();

    // ---- top-2 by key = (area<<15) | (BIGL - label), scan run heads only ----
    int bg = s_bg;
    unsigned b1 = 0, b2 = 0;
    if (tid == 0 && bg > 0) b1 = ((unsigned)bg << 15);
    {
        unsigned m = fgbits & ~(fgbits << 1);     // chunk-local run heads
        while (m) {
            int k = __ffs(m) - 1; m &= m - 1;
            int h = base + k;
            int e = L[h];
            if ((e & 0xFFFF) == h && (e >> 16) != 0) {
                unsigned key = ((unsigned)(e >> 16) << 15) | (unsigned)(BIGL - h);
                if (key > b1) { b2 = b1; b1 = key; }
                else if (key > b2) b2 = key;
            }
        }
    }
    for (int o = 32; o; o >>= 1) {
        unsigned p1 = __shfl_xor(b1, o, 64);
        unsigned p2 = __shfl_xor(b2, o, 64);
        if (p1 > b1) { b2 = (b1 > p2 ? b1 : p2); b1 = p1; }
        else if (p1 > b2) b2 = p1;
    }
    if (lane == 0) { s_wk[wid * 2] = b1; s_wk[wid * 2 + 1] = b2; }
    __syncthreads();
    if (tid < 64) {
        unsigned o1 = (tid < 16) ? s_wk[tid * 2] : 0u;
        unsigned o2 = (tid < 16) ? s_wk[tid * 2 + 1] : 0u;
        for (int o = 8; o; o >>= 1) {
            unsigned p1 = __shfl_xor(o1, o, 64);
            unsigned p2 = __shfl_xor(o2, o, 64);
            if (p1 > o1) { o2 = (o1 > p2 ? o1 : p2); o1 = p1; }
            else if (p1 > o2) o2 = p1;
        }
        if (tid == 0) s_k2 = o2;
    }
    __syncthreads();

    unsigned k2 = s_k2;
    bool have2 = (k2 >> 15) != 0;
    int j = BIGL - (int)(k2 & 0x7FFFu);      // runner-up label (BIGL == background)

    // ---- bbox of component j (wave-combined atomics) ----
    if (have2) {
        int lc0 = WW, lc1 = -1;
#pragma unroll
        for (int k = 0; k < PPT; ++k) {
            bool inc = (fgbits & (1u << k)) ? (rr[k] == j) : (j == BIGL);
            if (inc) {
                int c = col0 + k;
                lc0 = min(lc0, c); lc1 = max(lc1, c);
            }
        }
        int lr0 = (lc1 >= 0) ? row : HH;
        int lr1 = (lc1 >= 0) ? row : -1;
        lr0 = wmini(lr0); lr1 = wmaxi(lr1);
        lc0 = wmini(lc0); lc1 = wmaxi(lc1);
        if (lane == 0 && lr1 >= 0) {
            atomicMin(&s_r0, lr0); atomicMax(&s_r1, lr1);
            atomicMin(&s_c0, lc0); atomicMax(&s_c1, lc1);
        }
    }
    __syncthreads();

    // ---- sum inside box (from registers) ----
    float bsum = 0.f;
    if (have2) {
        int r0 = s_r0, r1 = s_r1, c0 = s_c0, c1 = s_c1;
        if (row >= r0 && row <= r1) {
#pragma unroll
            for (int k = 0; k < PPT; ++k) {
                int c = col0 + k;
                if (c >= c0 && c <= c1) bsum += vals[k];
            }
        }
    }
    bsum = wsumf(bsum);
    __syncthreads();
    if (lane == 0) s_wsum[wid] = bsum;
    __syncthreads();
    if (tid < 64) {
        float t = (tid < 16) ? s_wsum[tid] : 0.f;
        for (int o = 8; o; o >>= 1) t += __shfl_xor(t, o, 64);
        if (tid == 0) losses[blockIdx.x] = (s_total - t) * (1.0f / 16384.0f);
    }
}

__global__ void reduce_kernel(const float* __restrict__ losses, float* __restrict__ out, int n) {
    __shared__ float s[4];
    int t = threadIdx.x;                      // 256 threads
    float v = 0.f;
    for (int i = t; i < n; i += 256) v += losses[i];
    for (int off = 32; off; off >>= 1) v += __shfl_down(v, off, 64);
    if ((t & 63) == 0) s[t >> 6] = v;
    __syncthreads();
    if (t == 0) out[0] = (s[0] + s[1] + s[2] + s[3]) / (float)n;
}

extern "C" void kernel_launch(void* const* d_in, const int* in_sizes, int n_in,
                              void* d_out, int out_size, void* d_ws, size_t ws_size,
                              hipStream_t stream) {
    const float* masks = (const float*)d_in[0];
    float* out = (float*)d_out;
    float* losses = (float*)d_ws;
    int nmask = in_sizes[0] / HWPX;          // 8*16 = 128
    cc_kernel<<<nmask, NT, 0, stream>>>(masks, losses);
    reduce_kernel<<<1, 256, 0, stream>>>(losses, out, nmask);
}

// Round 9
// 51.540 us; speedup vs baseline: 2.4565x; 2.4565x over previous
//
#include <hip/hip_runtime.h>
#include <hip/hip_bf16.h>
#include <stdint.h>

#define HH 128
#define WW 128
#define HWPX 16384
#define BIGL 16384           // background sentinel (full image)
#define NT 1024

// find with path-halving via atomicMin (monotone decrease -> acyclic, safe
// under concurrent unions; R4-validated fastest variant)
__device__ __forceinline__ int findRootH(int* L, int x) {
    int p = L[x];
    while (p != x) {
        int g = L[p];
        if (g != p) atomicMin(&L[x], g);
        x = p; p = g;
    }
    return x;
}
// post-merge find with plain-store halving (no concurrent unions)
__device__ __forceinline__ int findRootF(int* L, int x) {
    int p = L[x];
    while (p != x) {
        int g = L[p];
        if (g != p) L[x] = g;
        x = p; p = g;
    }
    return p;
}
// lock-free union by min index
__device__ __forceinline__ void uni(int* L, int a, int b) {
    a = findRootH(L, a);
    b = findRootH(L, b);
    while (a != b) {
        if (a > b) { int t = a; a = b; b = t; }
        int old = atomicMin(&L[b], a);
        if (old == b) break;
        b = findRootH(L, old);
    }
}

__device__ __forceinline__ int wsumi(int v)    { for (int o = 32; o; o >>= 1) v += __shfl_xor(v, o, 64); return v; }
__device__ __forceinline__ float wsumf(float v){ for (int o = 32; o; o >>= 1) v += __shfl_xor(v, o, 64); return v; }
__device__ __forceinline__ int wmini(int v)    { for (int o = 32; o; o >>= 1) v = min(v, __shfl_xor(v, o, 64)); return v; }
__device__ __forceinline__ int wmaxi(int v)    { for (int o = 32; o; o >>= 1) v = max(v, __shfl_xor(v, o, 64)); return v; }

// ================= K1: per-half local CCL (256 blocks) =================
// Block b: image b>>1, half b&1 (64 rows). Local UF over 8192 px in LDS,
// labels = local min flat index. Output: u16 root-per-pixel (0xFFFF = bg),
// value = local_root + half*8192 (global-flat within image). Also per-half sum.
__global__ __launch_bounds__(NT)
void cc_half_kernel(const float* __restrict__ masks, unsigned short* __restrict__ labs,
                    float* __restrict__ sums) {
    __shared__ int L[8192];              // 32 KB local UF parents
    __shared__ unsigned rowbits[64][4];  // 1 KB fg bitmap (local rows)
    __shared__ float s_wsum[16];

    const int tid  = threadIdx.x;
    const int lane = tid & 63;
    const int wid  = tid >> 6;
    const int im   = blockIdx.x >> 1;
    const int h    = blockIdx.x & 1;
    const float* msk = masks + ((size_t)im << 14) + h * 8192;
    const int base = tid * 8;            // 8 px per thread
    const int rl   = tid >> 4;           // local row (16 threads per row)
    const int col0 = (tid & 15) * 8;

    // load 8 px, fg detect, run-head labels (local indices), sum
    float4 v0 = ((const float4*)(msk + base))[0];
    float4 v1 = ((const float4*)(msk + base))[1];
    float vals[8] = {v0.x, v0.y, v0.z, v0.w, v1.x, v1.y, v1.z, v1.w};
    unsigned fg = 0;
    float tsum = 0.f;
    int lab[8];
    {
        int start = -1;
#pragma unroll
        for (int k = 0; k < 8; ++k) {
            tsum += vals[k];
            if (vals[k] > 0.f) {
                fg |= 1u << k;
                if (start < 0) start = k;
                lab[k] = base + start;
            } else { start = -1; lab[k] = 8192; }
        }
    }
    {
        int4* Lv = (int4*)(L + base);
        Lv[0] = make_int4(lab[0], lab[1], lab[2], lab[3]);
        Lv[1] = make_int4(lab[4], lab[5], lab[6], lab[7]);
    }
    // edge bits from neighbor chunks (same wave: 16 chunks/row, 4 rows/wave)
    unsigned lf = __shfl(fg, lane > 0 ? lane - 1 : lane, 64);
    unsigned rf = __shfl(fg, lane < 63 ? lane + 1 : lane, 64);
    const unsigned leftbit  = (col0 > 0)   ? ((lf >> 7) & 1u) : 0u;
    const unsigned rightbit = (col0 < 120) ? (rf & 1u)        : 0u;
    // fg bitmap: 4 consecutive lanes -> one 32-bit word
    unsigned b1_ = __shfl(fg, lane + 1, 64);
    unsigned b2_ = __shfl(fg, lane + 2, 64);
    unsigned b3_ = __shfl(fg, lane + 3, 64);
    if ((lane & 3) == 0)
        rowbits[rl][(tid & 15) >> 2] = fg | (b1_ << 8) | (b2_ << 16) | (b3_ << 24);

    tsum = wsumf(tsum);
    if (lane == 0) s_wsum[wid] = tsum;
    __syncthreads();
    if (tid < 64) {
        float t = (tid < 16) ? s_wsum[tid] : 0.f;
        for (int o = 8; o; o >>= 1) t += __shfl_xor(t, o, 64);
        if (tid == 0) sums[im * 2 + h] = t;
    }

    // merge: event-masked dedup'd unions (all-concurrent; R8 showed sync hurts)
    if (fg) {
        unsigned up10 = 0;
        if (rl > 0) {
            const int wi  = col0 >> 5;
            const int off = col0 & 31;
            unsigned w0 = rowbits[rl - 1][wi];
            unsigned w1 = (wi < 3) ? rowbits[rl - 1][wi + 1] : 0u;
            unsigned long long uv = ((unsigned long long)w1 << 32) | w0;
            if (off) up10 = (unsigned)(uv >> (off - 1)) & 0x3FFu;
            else {
                unsigned lw = wi ? rowbits[rl - 1][wi - 1] : 0u;
                up10 = (unsigned)((uv << 1) | (lw >> 31)) & 0x3FFu;
            }
        }
        if ((fg & 1u) && leftbit) uni(L, base, base - 1);
        const unsigned ULv = up10 & 0xFFu;
        const unsigned UPv = (up10 >> 1) & 0xFFu;
        const unsigned URv = (up10 >> 2) & 0xFFu;
        const unsigned lFv = ((fg << 1) | leftbit) & 0xFFu;
        const unsigned rFv = (fg >> 1) | (rightbit << 7);
        unsigned m = fg & ( (~lFv & (ULv | UPv | URv))
                          | (lFv & ((UPv & ~ULv) | (~rFv & URv & ~UPv))) );
        while (m) {
            int k = __ffs(m) - 1; m &= m - 1;
            int i = base + k;
            unsigned UL = (ULv >> k) & 1u;
            unsigned UP = (UPv >> k) & 1u;
            unsigned UR = (URv >> k) & 1u;
            unsigned lF = (lFv >> k) & 1u;
            unsigned rF = (rFv >> k) & 1u;
            if (!lF) {
                if (UL)        uni(L, i, i - WW - 1);
                if (UP && !UL) uni(L, i, i - WW);
                if (UR && !UP) uni(L, i, i - WW + 1);
            } else {
                if (UP && !UL)        uni(L, i, i - WW);
                if (!rF && UR && !UP) uni(L, i, i - WW + 1);
            }
        }
    }
    __syncthreads();

    // flatten: one find per run; output u16 roots (global-flat within image)
    const int off16 = h * 8192;
    unsigned short o[8];
    {
        int cur = -1;
#pragma unroll
        for (int k = 0; k < 8; ++k) {
            if (fg & (1u << k)) {
                if (k == 0 || !(fg & (1u << (k - 1)))) cur = findRootF(L, base + k);
                o[k] = (unsigned short)(cur + off16);
            } else o[k] = 0xFFFFu;
        }
    }
    int4 w;
    w.x = (int)o[0] | ((int)o[1] << 16);
    w.y = (int)o[2] | ((int)o[3] << 16);
    w.z = (int)o[4] | ((int)o[5] << 16);
    w.w = (int)o[6] | ((int)o[7] << 16);
    ((int4*)(labs + ((size_t)im << 14) + off16 + base))[0] = w;
}

// ================= K2: per-image seam merge + stats (128 blocks) =================
__global__ __launch_bounds__(NT)
void cc_stats_kernel(const float* __restrict__ masks, const unsigned short* __restrict__ labs,
                     const float* __restrict__ sums, float* __restrict__ losses) {
    __shared__ int L[HWPX];              // 64 KB: depth<=1 forest; roots get area<<16
    __shared__ unsigned rowbits[HH][4];  // 2 KB
    __shared__ int s_bg;
    __shared__ int s_r0, s_r1, s_c0, s_c1;
    __shared__ unsigned s_k2;
    __shared__ unsigned s_wk[32];
    __shared__ float s_wsum[16];
    __shared__ float s_total;

    const int tid  = threadIdx.x;
    const int lane = tid & 63;
    const int wid  = tid >> 6;
    const int im   = blockIdx.x;
    const int base = tid * 16;
    const int row  = base >> 7;
    const int col0 = base & 127;

    // load labels (32B/thread), expand to int parents, build fg bits
    const int4* lp = (const int4*)(labs + ((size_t)im << 14) + base);
    int4 a = lp[0], b = lp[1];
    int li[16];
    li[0]=a.x&0xFFFF; li[1]=(a.x>>16)&0xFFFF; li[2]=a.y&0xFFFF; li[3]=(a.y>>16)&0xFFFF;
    li[4]=a.z&0xFFFF; li[5]=(a.z>>16)&0xFFFF; li[6]=a.w&0xFFFF; li[7]=(a.w>>16)&0xFFFF;
    li[8]=b.x&0xFFFF; li[9]=(b.x>>16)&0xFFFF; li[10]=b.y&0xFFFF; li[11]=(b.y>>16)&0xFFFF;
    li[12]=b.z&0xFFFF; li[13]=(b.z>>16)&0xFFFF; li[14]=b.w&0xFFFF; li[15]=(b.w>>16)&0xFFFF;
    unsigned fgbits = 0;
    int lab[16];
#pragma unroll
    for (int k = 0; k < 16; ++k) {
        if (li[k] != 0xFFFF) { fgbits |= 1u << k; lab[k] = li[k]; }
        else lab[k] = BIGL;
    }
    {
        int4* Lv = (int4*)(L + base);
#pragma unroll
        for (int q = 0; q < 4; ++q)
            Lv[q] = make_int4(lab[q*4], lab[q*4+1], lab[q*4+2], lab[q*4+3]);
    }
    unsigned lf = __shfl(fgbits, lane > 0 ? lane - 1 : lane, 64);
    unsigned rf = __shfl(fgbits, lane < 63 ? lane + 1 : lane, 64);
    const unsigned leftbit  = (col0 > 0)   ? ((lf >> 15) & 1u) : 0u;
    const unsigned rightbit = (col0 < 112) ? (rf & 1u)         : 0u;
    unsigned other = __shfl_xor(fgbits, 1, 64);
    if (!(tid & 1)) rowbits[row][(tid >> 1) & 3] = fgbits | (other << 16);
    if (tid == 0) {
        s_bg = 0; s_r0 = HH; s_r1 = -1; s_c0 = WW; s_c1 = -1;
        s_total = sums[im * 2] + sums[im * 2 + 1];
    }
    __syncthreads();

    // seam unions: only row 64 (upper = row 63), same event rules
    if (row == 64 && fgbits) {
        unsigned up = 0;
        {
            const int wi  = col0 >> 5;
            const int off = col0 & 31;
            unsigned w0 = rowbits[63][wi];
            unsigned w1 = (wi < 3) ? rowbits[63][wi + 1] : 0u;
            unsigned long long uv = ((unsigned long long)w1 << 32) | w0;
            if (off == 16) up = (unsigned)(uv >> 15) & 0x3FFFFu;
            else {
                unsigned lw = (col0 > 0) ? rowbits[63][wi - 1] : 0u;
                up = (unsigned)((uv << 1) | (lw >> 31)) & 0x3FFFFu;
            }
        }
        const unsigned ULv = up & 0xFFFFu;
        const unsigned UPv = (up >> 1) & 0xFFFFu;
        const unsigned URv = (up >> 2) & 0xFFFFu;
        const unsigned lFv = ((fgbits << 1) | leftbit) & 0xFFFFu;
        const unsigned rFv = (fgbits >> 1) | (rightbit << 15);
        unsigned m = fgbits & ( (~lFv & (ULv | UPv | URv))
                              | (lFv & ((UPv & ~ULv) | (~rFv & URv & ~UPv))) );
        while (m) {
            int k = __ffs(m) - 1; m &= m - 1;
            int i = base + k;
            unsigned UL = (ULv >> k) & 1u;
            unsigned UP = (UPv >> k) & 1u;
            unsigned UR = (URv >> k) & 1u;
            unsigned lF = (lFv >> k) & 1u;
            unsigned rF = (rFv >> k) & 1u;
            if (!lF) {
                if (UL)        uni(L, i, i - WW - 1);
                if (UP && !UL) uni(L, i, i - WW);
                if (UR && !UP) uni(L, i, i - WW + 1);
            } else {
                if (UP && !UL)        uni(L, i, i - WW);
                if (!rF && UR && !UP) uni(L, i, i - WW + 1);
            }
        }
    }
    __syncthreads();

    // flatten (depth <= 2 now), compress run heads, track first root
    int rr[16];
    int firstRoot = 0x7FFFFFFF;
    {
        int cur = -1;
#pragma unroll
        for (int k = 0; k < 16; ++k) {
            rr[k] = -1;
            if (fgbits & (1u << k)) {
                if (k == 0 || !(fgbits & (1u << (k - 1)))) {
                    cur = findRootF(L, base + k);
                    L[base + k] = cur;
                }
                rr[k] = cur;
                if (firstRoot == 0x7FFFFFFF) firstRoot = cur;
            }
        }
    }
    __syncthreads();

    // areas: wave-combined dominant root + run-length atomics
    {
        const int R0 = wmini(firstRoot);
        int giant = 0, bgc = 0, prev = -1, cnt = 0;
#pragma unroll
        for (int k = 0; k < 16; ++k) {
            if (!(fgbits & (1u << k))) { ++bgc; continue; }
            int r = rr[k];
            if (r == R0) ++giant;
            else if (r == prev) ++cnt;
            else {
                if (cnt) atomicAdd(&L[prev], cnt << 16);
                prev = r; cnt = 1;
            }
        }
        if (cnt) atomicAdd(&L[prev], cnt << 16);
        int g = wsumi(giant);
        if (lane == 0 && R0 != 0x7FFFFFFF && g) atomicAdd(&L[R0], g << 16);
        int bq = wsumi(bgc);
        if (lane == 0 && bq) atomicAdd(&s_bg, bq);
    }
    __syncthreads();

    // top-2 by key = (area<<15) | (BIGL - label), run heads only
    int bg = s_bg;
    unsigned b1 = 0, b2 = 0;
    if (tid == 0 && bg > 0) b1 = ((unsigned)bg << 15);
    {
        unsigned m = fgbits & ~(fgbits << 1);
        while (m) {
            int k = __ffs(m) - 1; m &= m - 1;
            int hh = base + k;
            int e = L[hh];
            if ((e & 0xFFFF) == hh && (e >> 16) != 0) {
                unsigned key = ((unsigned)(e >> 16) << 15) | (unsigned)(BIGL - hh);
                if (key > b1) { b2 = b1; b1 = key; }
                else if (key > b2) b2 = key;
            }
        }
    }
    for (int o = 32; o; o >>= 1) {
        unsigned p1 = __shfl_xor(b1, o, 64);
        unsigned p2 = __shfl_xor(b2, o, 64);
        if (p1 > b1) { b2 = (b1 > p2 ? b1 : p2); b1 = p1; }
        else if (p1 > b2) b2 = p1;
    }
    if (lane == 0) { s_wk[wid * 2] = b1; s_wk[wid * 2 + 1] = b2; }
    __syncthreads();
    if (tid < 64) {
        unsigned o1 = (tid < 16) ? s_wk[tid * 2] : 0u;
        unsigned o2 = (tid < 16) ? s_wk[tid * 2 + 1] : 0u;
        for (int o = 8; o; o >>= 1) {
            unsigned p1 = __shfl_xor(o1, o, 64);
            unsigned p2 = __shfl_xor(o2, o, 64);
            if (p1 > o1) { o2 = (o1 > p2 ? o1 : p2); o1 = p1; }
            else if (p1 > o2) o2 = p1;
        }
        if (tid == 0) s_k2 = o2;
    }
    __syncthreads();

    unsigned k2 = s_k2;
    bool have2 = (k2 >> 15) != 0;
    int j = BIGL - (int)(k2 & 0x7FFFu);

    // bbox of runner-up (wave-combined)
    if (have2) {
        int lc0 = WW, lc1 = -1;
#pragma unroll
        for (int k = 0; k < 16; ++k) {
            bool inc = (fgbits & (1u << k)) ? (rr[k] == j) : (j == BIGL);
            if (inc) {
                int c = col0 + k;
                lc0 = min(lc0, c); lc1 = max(lc1, c);
            }
        }
        int lr0 = (lc1 >= 0) ? row : HH;
        int lr1 = (lc1 >= 0) ? row : -1;
        lr0 = wmini(lr0); lr1 = wmaxi(lr1);
        lc0 = wmini(lc0); lc1 = wmaxi(lc1);
        if (lane == 0 && lr1 >= 0) {
            atomicMin(&s_r0, lr0); atomicMax(&s_r1, lr1);
            atomicMin(&s_c0, lc0); atomicMax(&s_c1, lc1);
        }
    }
    __syncthreads();

    // box sum: re-read mask (L2-warm) only for rows inside the box
    float bsum = 0.f;
    if (have2) {
        int r0 = s_r0, r1 = s_r1, c0 = s_c0, c1 = s_c1;
        if (row >= r0 && row <= r1) {
            const float* msk = masks + ((size_t)im << 14);
            const float4* m4 = (const float4*)(msk + base);
#pragma unroll
            for (int q = 0; q < 4; ++q) {
                float4 v = m4[q];
                float vv[4] = {v.x, v.y, v.z, v.w};
#pragma unroll
                for (int t = 0; t < 4; ++t) {
                    int c = col0 + q * 4 + t;
                    if (c >= c0 && c <= c1) bsum += vv[t];
                }
            }
        }
    }
    bsum = wsumf(bsum);
    __syncthreads();
    if (lane == 0) s_wsum[wid] = bsum;
    __syncthreads();
    if (tid < 64) {
        float t = (tid < 16) ? s_wsum[tid] : 0.f;
        for (int o = 8; o; o >>= 1) t += __shfl_xor(t, o, 64);
        if (tid == 0) losses[im] = (s_total - t) * (1.0f / 16384.0f);
    }
}

// ================= fallback: R7 single-kernel path (ws too small) =================
__global__ __launch_bounds__(NT)
void cc_fallback(const float* __restrict__ masks, float* __restrict__ losses) {
    __shared__ int L[HWPX];
    __shared__ unsigned rowbits[HH][4];
    __shared__ int s_bg;
    __shared__ int s_r0, s_r1, s_c0, s_c1;
    __shared__ unsigned s_k2;
    __shared__ unsigned s_wk[32];
    __shared__ float s_wsum[16];
    __shared__ float s_total;

    const int tid = threadIdx.x;
    const int lane = tid & 63;
    const int wid = tid >> 6;
    const float* msk = masks + (size_t)blockIdx.x * HWPX;
    const int base = tid * 16;
    const int row  = base >> 7;
    const int col0 = base & 127;

    float vals[16];
    const float4* m4 = (const float4*)(msk + base);
#pragma unroll
    for (int q = 0; q < 4; ++q) {
        float4 v = m4[q];
        vals[q*4+0]=v.x; vals[q*4+1]=v.y; vals[q*4+2]=v.z; vals[q*4+3]=v.w;
    }
    unsigned fgbits = 0;
    float tsum = 0.f;
    int lab[16];
    {
        int start = -1;
#pragma unroll
        for (int k = 0; k < 16; ++k) {
            tsum += vals[k];
            if (vals[k] > 0.f) {
                fgbits |= 1u << k;
                if (start < 0) start = k;
                lab[k] = base + start;
            } else { start = -1; lab[k] = BIGL; }
        }
    }
    {
        int4* Lv = (int4*)(L + base);
#pragma unroll
        for (int q = 0; q < 4; ++q)
            Lv[q] = make_int4(lab[q*4], lab[q*4+1], lab[q*4+2], lab[q*4+3]);
    }
    unsigned lf = __shfl(fgbits, lane > 0 ? lane - 1 : lane, 64);
    unsigned rf = __shfl(fgbits, lane < 63 ? lane + 1 : lane, 64);
    const unsigned leftbit  = (col0 > 0)   ? ((lf >> 15) & 1u) : 0u;
    const unsigned rightbit = (col0 < 112) ? (rf & 1u)         : 0u;
    unsigned other = __shfl_xor(fgbits, 1, 64);
    if (!(tid & 1)) rowbits[row][(tid >> 1) & 3] = fgbits | (other << 16);

    tsum = wsumf(tsum);
    if (lane == 0) s_wsum[wid] = tsum;
    if (tid == 0) { s_bg = 0; s_r0 = HH; s_r1 = -1; s_c0 = WW; s_c1 = -1; }
    __syncthreads();
    if (tid < 64) {
        float t = (tid < 16) ? s_wsum[tid] : 0.f;
        for (int o = 8; o; o >>= 1) t += __shfl_xor(t, o, 64);
        if (tid == 0) s_total = t;
    }
    if (fgbits) {
        unsigned up = 0;
        if (row > 0) {
            const int wi  = col0 >> 5;
            const int off = col0 & 31;
            unsigned w0 = rowbits[row - 1][wi];
            unsigned w1 = (wi < 3) ? rowbits[row - 1][wi + 1] : 0u;
            unsigned long long uv = ((unsigned long long)w1 << 32) | w0;
            if (off == 16) up = (unsigned)(uv >> 15) & 0x3FFFFu;
            else {
                unsigned lw = (col0 > 0) ? rowbits[row - 1][wi - 1] : 0u;
                up = (unsigned)((uv << 1) | (lw >> 31)) & 0x3FFFFu;
            }
        }
        if ((fgbits & 1u) && leftbit) uni(L, base, base - 1);
        const unsigned ULv = up & 0xFFFFu;
        const unsigned UPv = (up >> 1) & 0xFFFFu;
        const unsigned URv = (up >> 2) & 0xFFFFu;
        const unsigned lFv = ((fgbits << 1) | leftbit) & 0xFFFFu;
        const unsigned rFv = (fgbits >> 1) | (rightbit << 15);
        unsigned m = fgbits & ( (~lFv & (ULv | UPv | URv))
                              | (lFv & ((UPv & ~ULv) | (~rFv & URv & ~UPv))) );
        while (m) {
            int k = __ffs(m) - 1; m &= m - 1;
            int i = base + k;
            unsigned UL = (ULv >> k) & 1u;
            unsigned UP = (UPv >> k) & 1u;
            unsigned UR = (URv >> k) & 1u;
            unsigned lF = (lFv >> k) & 1u;
            unsigned rF = (rFv >> k) & 1u;
            if (!lF) {
                if (UL)        uni(L, i, i - WW - 1);
                if (UP && !UL) uni(L, i, i - WW);
                if (UR && !UP) uni(L, i, i - WW + 1);
            } else {
                if (UP && !UL)        uni(L, i, i - WW);
                if (!rF && UR && !UP) uni(L, i, i - WW + 1);
            }
        }
    }
    __syncthreads();
    int rr[16];
    int firstRoot = 0x7FFFFFFF;
    {
        int cur = -1;
#pragma unroll
        for (int k = 0; k < 16; ++k) {
            rr[k] = -1;
            if (fgbits & (1u << k)) {
                if (k == 0 || !(fgbits & (1u << (k - 1)))) {
                    cur = findRootF(L, base + k);
                    L[base + k] = cur;
                }
                rr[k] = cur;
                if (firstRoot == 0x7FFFFFFF) firstRoot = cur;
            }
        }
    }
    __syncthreads();
    {
        const int R0 = wmini(firstRoot);
        int giant = 0, bgc = 0, prev = -1, cnt = 0;
#pragma unroll
        for (int k = 0; k < 16; ++k) {
            if (!(fgbits & (1u << k))) { ++bgc; continue; }
            int r = rr[k];
            if (r == R0) ++giant;
            else if (r == prev) ++cnt;
            else {
                if (cnt) atomicAdd(&L[prev], cnt << 16);
                prev = r; cnt = 1;
            }
        }
        if (cnt) atomicAdd(&L[prev], cnt << 16);
        int g = wsumi(giant);
        if (lane == 0 && R0 != 0x7FFFFFFF && g) atomicAdd(&L[R0], g << 16);
        int bq = wsumi(bgc);
        if (lane == 0 && bq) atomicAdd(&s_bg, bq);
    }
    __syncthreads();
    int bg = s_bg;
    unsigned b1 = 0, b2 = 0;
    if (tid == 0 && bg > 0) b1 = ((unsigned)bg << 15);
    {
        unsigned m = fgbits & ~(fgbits << 1);
        while (m) {
            int k = __ffs(m) - 1; m &= m - 1;
            int hh = base + k;
            int e = L[hh];
            if ((e & 0xFFFF) == hh && (e >> 16) != 0) {
                unsigned key = ((unsigned)(e >> 16) << 15) | (unsigned)(BIGL - hh);
                if (key > b1) { b2 = b1; b1 = key; }
                else if (key > b2) b2 = key;
            }
        }
    }
    for (int o = 32; o; o >>= 1) {
        unsigned p1 = __shfl_xor(b1, o, 64);
        unsigned p2 = __shfl_xor(b2, o, 64);
        if (p1 > b1) { b2 = (b1 > p2 ? b1 : p2); b1 = p1; }
        else if (p1 > b2) b2 = p1;
    }
    if (lane == 0) { s_wk[wid * 2] = b1; s_wk[wid * 2 + 1] = b2; }
    __syncthreads();
    if (tid < 64) {
        unsigned o1 = (tid < 16) ? s_wk[tid * 2] : 0u;
        unsigned o2 = (tid < 16) ? s_wk[tid * 2 + 1] : 0u;
        for (int o = 8; o; o >>= 1) {
            unsigned p1 = __shfl_xor(o1, o, 64);
            unsigned p2 = __shfl_xor(o2, o, 64);
            if (p1 > o1) { o2 = (o1 > p2 ? o1 : p2); o1 = p1; }
            else if (p1 > o2) o2 = p1;
        }
        if (tid == 0) s_k2 = o2;
    }
    __syncthreads();
    unsigned k2 = s_k2;
    bool have2 = (k2 >> 15) != 0;
    int j = BIGL - (int)(k2 & 0x7FFFu);
    if (have2) {
        int lc0 = WW, lc1 = -1;
#pragma unroll
        for (int k = 0; k < 16; ++k) {
            bool inc = (fgbits & (1u << k)) ? (rr[k] == j) : (j == BIGL);
            if (inc) {
                int c = col0 + k;
                lc0 = min(lc0, c); lc1 = max(lc1, c);
            }
        }
        int lr0 = (lc1 >= 0) ? row : HH;
        int lr1 = (lc1 >= 0) ? row : -1;
        lr0 = wmini(lr0); lr1 = wmaxi(lr1);
        lc0 = wmini(lc0); lc1 = wmaxi(lc1);
        if (lane == 0 && lr1 >= 0) {
            atomicMin(&s_r0, lr0); atomicMax(&s_r1, lr1);
            atomicMin(&s_c0, lc0); atomicMax(&s_c1, lc1);
        }
    }
    __syncthreads();
    float bsum = 0.f;
    if (have2) {
        int r0 = s_r0, r1 = s_r1, c0 = s_c0, c1 = s_c1;
        if (row >= r0 && row <= r1) {
#pragma unroll
            for (int k = 0; k < 16; ++k) {
                int c = col0 + k;
                if (c >= c0 && c <= c1) bsum += vals[k];
            }
        }
    }
    bsum = wsumf(bsum);
    __syncthreads();
    if (lane == 0) s_wsum[wid] = bsum;
    __syncthreads();
    if (tid < 64) {
        float t = (tid < 16) ? s_wsum[tid] : 0.f;
        for (int o = 8; o; o >>= 1) t += __shfl_xor(t, o, 64);
        if (tid == 0) losses[blockIdx.x] = (s_total - t) * (1.0f / 16384.0f);
    }
}

__global__ void reduce_kernel(const float* __restrict__ losses, float* __restrict__ out, int n) {
    __shared__ float s[4];
    int t = threadIdx.x;                      // 256 threads
    float v = 0.f;
    for (int i = t; i < n; i += 256) v += losses[i];
    for (int off = 32; off; off >>= 1) v += __shfl_down(v, off, 64);
    if ((t & 63) == 0) s[t >> 6] = v;
    __syncthreads();
    if (t == 0) out[0] = (s[0] + s[1] + s[2] + s[3]) / (float)n;
}

extern "C" void kernel_launch(void* const* d_in, const int* in_sizes, int n_in,
                              void* d_out, int out_size, void* d_ws, size_t ws_size,
                              hipStream_t stream) {
    const float* masks = (const float*)d_in[0];
    float* out = (float*)d_out;
    int nmask = in_sizes[0] / HWPX;          // 128
    char* w = (char*)d_ws;
    size_t labBytes  = (size_t)nmask * HWPX * 2;       // u16 labels
    size_t sumsBytes = (size_t)nmask * 2 * 4;          // per-half sums
    size_t need = labBytes + sumsBytes + (size_t)nmask * 4;
    if (ws_size >= need) {
        unsigned short* labs = (unsigned short*)w;
        float* sums   = (float*)(w + labBytes);
        float* losses = (float*)(w + labBytes + sumsBytes);
        cc_half_kernel<<<nmask * 2, NT, 0, stream>>>(masks, labs, sums);
        cc_stats_kernel<<<nmask, NT, 0, stream>>>(masks, labs, sums, losses);
        reduce_kernel<<<1, 256, 0, stream>>>(losses, out, nmask);
    } else {
        float* losses = (float*)d_ws;
        cc_fallback<<<nmask, NT, 0, stream>>>(masks, losses);
        reduce_kernel<<<1, 256, 0, stream>>>(losses, out, nmask);
    }
}